// Round 7
// baseline (394.129 us; speedup 1.0000x reference)
//
#include <hip/hip_runtime.h>
#include <stdint.h>

#define BB 32
#define CC_ 256
#define HH 56
#define WW 56
#define TW 28          // W-tile width (2 tiles per row)
#define TCOLS 30       // TW + 2 halo columns
#define EPSV 1e-5f

typedef unsigned long long u64;

// ---------------- Weight prep: alpha, packed signs, BN folding ----------------
__global__ __launch_bounds__(256) void prep_weights(
    const float* __restrict__ w1, const float* __restrict__ w2,
    const float* __restrict__ bn1_g, const float* __restrict__ bn1_b,
    const float* __restrict__ bn1_m, const float* __restrict__ bn1_v,
    const float* __restrict__ bn2_g, const float* __restrict__ bn2_b,
    const float* __restrict__ bn2_m, const float* __restrict__ bn2_v,
    u64* __restrict__ pw1, u64* __restrict__ pw2,
    float* __restrict__ scale1, float* __restrict__ shift1,
    float* __restrict__ scale2, float* __restrict__ shift2)
{
    int co = blockIdx.x;
    int ci = threadIdx.x;
    int wv = ci >> 6, lane = ci & 63;

    float wvals[9];
    const float* wp = w1 + ((size_t)co*256 + ci)*9;
    float s1 = 0.f;
#pragma unroll
    for (int t = 0; t < 9; ++t) { wvals[t] = wp[t]; s1 += fabsf(wvals[t]); }
    float v2 = w2[(size_t)co*256 + ci];
    float s2 = fabsf(v2);

    // ballot-pack signs: bit l of word wv  <->  channel 64*wv + l  (+1 iff > 0)
#pragma unroll
    for (int t = 0; t < 9; ++t) {
        u64 b = __ballot(wvals[t] > 0.0f);
        if (lane == 0) pw1[((size_t)co*9 + t)*4 + wv] = b;
    }
    {
        u64 b = __ballot(v2 > 0.0f);
        if (lane == 0) pw2[(size_t)co*4 + wv] = b;
    }

    for (int off = 32; off > 0; off >>= 1) {
        s1 += __shfl_down(s1, off);
        s2 += __shfl_down(s2, off);
    }
    __shared__ float r1[4], r2[4];
    if (lane == 0) { r1[wv] = s1; r2[wv] = s2; }
    __syncthreads();
    if (ci == 0) {
        float a1 = (r1[0]+r1[1]+r1[2]+r1[3]) * (1.0f/2304.0f);
        float a2 = (r2[0]+r2[1]+r2[2]+r2[3]) * (1.0f/256.0f);
        float inv1 = bn1_g[co] / sqrtf(bn1_v[co] + EPSV);
        float inv2 = bn2_g[co] / sqrtf(bn2_v[co] + EPSV);
        scale1[co] = a1 * inv1;
        shift1[co] = bn1_b[co] - bn1_m[co]*inv1;
        scale2[co] = a2 * inv2;
        shift2[co] = bn2_b[co] - bn2_m[co]*inv2;
    }
}

// ---------------- Pack input: coalesced LDS stage -> ballot transpose ----------------
__global__ __launch_bounds__(256) void pack_input(
    const float* __restrict__ x, const float* __restrict__ beta1,
    u64* __restrict__ pack1)
{
    __shared__ float xrow[CC_][WW+1];      // stride 57 -> ballot reads conflict-free
    int bid = blockIdx.x;                  // n*HH + h
    int n = bid / HH, h = bid % HH;
    int tid = threadIdx.x;

    for (int idx = tid; idx < CC_*14; idx += 256) {
        int c = idx / 14, g = idx - c*14;
        float4 v = *(const float4*)(x + (((size_t)n*CC_ + c)*HH + h)*WW + 4*g);
        xrow[c][4*g+0] = v.x; xrow[c][4*g+1] = v.y;
        xrow[c][4*g+2] = v.z; xrow[c][4*g+3] = v.w;
    }
    __syncthreads();

    int wv = tid >> 6, lane = tid & 63;
    float beta = beta1[wv*64 + lane];
    u64 mine = 0;
    for (int ww = 0; ww < WW; ++ww) {
        u64 b = __ballot(xrow[wv*64 + lane][ww] > beta);
        if (ww == lane) mine = b;
    }
    if (lane < WW) pack1[((size_t)bid*WW + lane)*4 + wv] = mine;
}

// ---------------- popcount helpers (all indices compile-time after expansion) ----------------
#define PC2(x0,x1,w0,w1) (__builtin_popcountll((x0)^(w0)) + __builtin_popcountll((x1)^(w1)))

#define ACC9(L,M,R) \
 ( PC2(L[0],L[1],Wh[0],Wh[1])   + PC2(M[0],M[1],Wh[2],Wh[3])   + PC2(R[0],R[1],Wh[4],Wh[5]) \
 + PC2(L[2],L[3],Wh[6],Wh[7])   + PC2(M[2],M[3],Wh[8],Wh[9])   + PC2(R[2],R[3],Wh[10],Wh[11]) \
 + PC2(L[4],L[5],Wh[12],Wh[13]) + PC2(M[4],M[5],Wh[14],Wh[15]) + PC2(R[4],R[5],Wh[16],Wh[17]) )

#define LOADCOL(D,J) do { \
    ulonglong2 t0_ = *(const ulonglong2*)&rows[0][(J)][hi2]; \
    ulonglong2 t1_ = *(const ulonglong2*)&rows[1][(J)][hi2]; \
    ulonglong2 t2_ = *(const ulonglong2*)&rows[2][(J)][hi2]; \
    D[0]=t0_.x; D[1]=t0_.y; D[2]=t1_.x; D[3]=t1_.y; D[4]=t2_.x; D[5]=t2_.y; } while(0)

#define STEP(L,M,R,P) do { \
    int acc_ = ACC9(L,M,R); \
    float cur_ = outr[cc][(P)]; \
    float val_ = fmaf((float)(1152 - 2*acc_), sc1, cur_); \
    if (passB) { val_ += sh1; float yr_ = val_ - gam; \
                 val_ = fmaf(slp, fminf(yr_,0.f), fmaxf(yr_,0.f)) + zet; } \
    outr[cc][(P)] = val_; } while(0)

// ---------------- Fused main (lane = cout, two ci-half passes, rotating window cols) ----------------
__global__ __launch_bounds__(256, 4) void main_fused(
    const float* __restrict__ x,
    const u64* __restrict__ pack1,
    const u64* __restrict__ pw1, const u64* __restrict__ pw2,
    const float* __restrict__ scale1, const float* __restrict__ shift1,
    const float* __restrict__ scale2, const float* __restrict__ shift2,
    const float* __restrict__ beta2,
    const float* __restrict__ pr_gamma, const float* __restrict__ pr_slope,
    const float* __restrict__ pr_zeta,
    float* __restrict__ out)
{
    __shared__ u64 rows[3][TCOLS][4];        // 2880 B
    __shared__ float outr[CC_][TW+1];        // 29696 B: x -> partial -> out_r -> final
    __shared__ u64 p2[TW][4];                // 896 B   (total 33472 B -> 4 blocks/CU)

    int bid = blockIdx.x;
    int tile = bid & 1;
    int nh = bid >> 1;
    int n = nh / HH, h = nh % HH;
    int w0 = tile * TW;
    int tid = threadIdx.x;
    int wv = tid >> 6;
    int lane = tid & 63;
    int cc = tid;                            // this thread's output channel

    float sc1 = scale1[cc], sh1 = shift1[cc];
    float sc2 = scale2[cc], sh2 = shift2[cc];
    float gam = pr_gamma[cc], slp = pr_slope[cc], zet = pr_zeta[cc];
    float bet2 = beta2[cc];
    const u64* wq = pw1 + (size_t)cc*36;     // [tap t][word q] q=0..3

    // ---- stage packed rows h-1,h,h+1 with w-halo (clamped; masked/fixed later) ----
    {
        int hm = (h > 0) ? h-1 : 0;
        int hp = (h < HH-1) ? h+1 : HH-1;
        for (int idx = tid; idx < 3*TCOLS*4; idx += 256) {
            int r = idx / (TCOLS*4);
            int rem = idx - r*(TCOLS*4);
            int j = rem >> 2, q = rem & 3;
            int gw = w0 - 1 + j;
            gw = (gw < 0) ? 0 : ((gw > WW-1) ? WW-1 : gw);
            int hr = (r == 0) ? hm : ((r == 1) ? h : hp);
            rows[r][j][q] = pack1[((size_t)(n*HH + hr)*WW + gw)*4 + q];
        }
    }
    // ---- stage residual x tile (coalesced float4) ----
    for (int idx = tid; idx < CC_*7; idx += 256) {
        int c = idx / 7, g = idx - c*7;
        float4 v = *(const float4*)(x + (((size_t)n*CC_ + c)*HH + h)*WW + w0 + 4*g);
        outr[c][4*g+0] = v.x; outr[c][4*g+1] = v.y;
        outr[c][4*g+2] = v.z; outr[c][4*g+3] = v.w;
    }
    __syncthreads();

    bool rowU = (h > 0), rowD = (h < HH-1);

    // ---- phase 1: 3x3 binary conv + BN + residual + RPReLU, two ci-half passes ----
    if (rowU && rowD) {
        // stash the edge pixel's residual (its in-loop value will be garbage until fix-up)
        float xe = (tile == 0) ? outr[cc][0] : outr[cc][TW-1];

        for (int hi2 = 0; hi2 <= 2; hi2 += 2) {      // ci half: words {0,1} then {2,3}
            bool passB = (hi2 != 0);
            u64 Wh[18];
#pragma unroll
            for (int t = 0; t < 9; ++t) {
                ulonglong2 v = *(const ulonglong2*)(wq + t*4 + hi2);
                Wh[2*t] = v.x; Wh[2*t+1] = v.y;
            }
            u64 wa[6], wb[6], wc[6];
            LOADCOL(wa, 0); LOADCOL(wb, 1);
            int p = 0;
            for (int it = 0; it < 9; ++it) {          // 27 pixels, rotation period 3
                LOADCOL(wc, p+2); STEP(wa, wb, wc, p);
                LOADCOL(wa, p+3); STEP(wb, wc, wa, p+1);
                LOADCOL(wb, p+4); STEP(wc, wa, wb, p+2);
                p += 3;
            }
            LOADCOL(wc, 29); STEP(wa, wb, wc, 27);    // tail pixel 27
        }

        // fix-up the single global-edge pixel (6 valid taps), exact recompute
        if (tile == 0) {
            int acc = 0;
#pragma unroll
            for (int r = 0; r < 3; ++r) {
#pragma unroll
                for (int dc = 1; dc <= 2; ++dc) {
                    const u64* wt = wq + (r*3+dc)*4;
                    acc += PC2(rows[r][dc][0], rows[r][dc][1], wt[0], wt[1])
                         + PC2(rows[r][dc][2], rows[r][dc][3], wt[2], wt[3]);
                }
            }
            float y = fmaf((float)(1536 - 2*acc), sc1, sh1) + xe;
            float yr = y - gam;
            outr[cc][0] = fmaf(slp, fminf(yr,0.f), fmaxf(yr,0.f)) + zet;
        } else {
            int acc = 0;
#pragma unroll
            for (int r = 0; r < 3; ++r) {
#pragma unroll
                for (int dc = 0; dc <= 1; ++dc) {
                    const u64* wt = wq + (r*3+dc)*4;
                    acc += PC2(rows[r][27+dc][0], rows[r][27+dc][1], wt[0], wt[1])
                         + PC2(rows[r][27+dc][2], rows[r][27+dc][3], wt[2], wt[3]);
                }
            }
            float y = fmaf((float)(1536 - 2*acc), sc1, sh1) + xe;
            float yr = y - gam;
            outr[cc][TW-1] = fmaf(slp, fminf(yr,0.f), fmaxf(yr,0.f)) + zet;
        }
    } else {
        // border-h blocks (h=0 or 55): masked taps, same two-pass accumulation
        for (int hi2 = 0; hi2 <= 2; hi2 += 2) {
            bool passB = (hi2 != 0);
            u64 Wh[18];
#pragma unroll
            for (int t = 0; t < 9; ++t) {
                ulonglong2 v = *(const ulonglong2*)(wq + t*4 + hi2);
                Wh[2*t] = v.x; Wh[2*t+1] = v.y;
            }
            for (int p = 0; p < TW; ++p) {
                int w = w0 + p;
                bool colL = (w > 0), colR = (w < WW-1);
                int acc = 0, nval = 0;
#pragma unroll
                for (int t = 0; t < 9; ++t) {
                    int r = t / 3, dc = t - 3*r;
                    bool v = ((r == 0) ? rowU : (r == 2) ? rowD : true)
                          && ((dc == 0) ? colL : (dc == 2) ? colR : true);
                    if (v) {
                        acc += PC2(rows[r][p+dc][hi2], rows[r][p+dc][hi2+1],
                                   Wh[2*t], Wh[2*t+1]);
                        ++nval;
                    }
                }
                float cur = outr[cc][p];
                float val = fmaf((float)(128*nval - 2*acc), sc1, cur);
                if (passB) {
                    val += sh1; float yr = val - gam;
                    val = fmaf(slp, fminf(yr,0.f), fmaxf(yr,0.f)) + zet;
                }
                outr[cc][p] = val;
            }
        }
    }
    // no barrier: phase 2 reads only this thread's own outr row

    // ---- phase 2: rsign(out_r, beta2) -> packed bits per pixel ----
    {
        u64 mine = 0;
        for (int ww = 0; ww < TW; ++ww) {
            u64 b = __ballot(outr[cc][ww] > bet2);
            if (ww == lane) mine = b;
        }
        if (lane < TW) p2[lane][wv] = mine;
    }
    __syncthreads();                         // p2 consumed cross-wave

    // ---- phase 3: 1x1 binary conv + BN + residual + RPReLU (in-place outr) ----
    {
        ulonglong2 qa = *(const ulonglong2*)(pw2 + (size_t)cc*4);
        ulonglong2 qb = *(const ulonglong2*)(pw2 + (size_t)cc*4 + 2);
        u64 q0 = qa.x, q1 = qa.y, q2 = qb.x, q3 = qb.y;
        for (int p = 0; p < TW; ++p) {
            ulonglong2 a = *(const ulonglong2*)&p2[p][0];
            ulonglong2 b = *(const ulonglong2*)&p2[p][2];
            int pc = PC2(a.x, a.y, q0, q1) + PC2(b.x, b.y, q2, q3);
            float s = (float)(256 - 2*pc);
            float y = fmaf(s, sc2, sh2) + outr[cc][p];
            float yr = y - gam;
            outr[cc][p] = fmaf(slp, fminf(yr,0.f), fmaxf(yr,0.f)) + zet;
        }
    }
    __syncthreads();                         // phase 4 reads other waves' rows

    // ---- phase 4: coalesced float4 write-out ----
    for (int idx = tid; idx < CC_*7; idx += 256) {
        int c = idx / 7, g = idx - c*7;
        float4 v;
        v.x = outr[c][4*g+0]; v.y = outr[c][4*g+1];
        v.z = outr[c][4*g+2]; v.w = outr[c][4*g+3];
        *(float4*)(out + (((size_t)n*CC_ + c)*HH + h)*WW + w0 + 4*g) = v;
    }
}

// ---------------- launcher ----------------
extern "C" void kernel_launch(void* const* d_in, const int* in_sizes, int n_in,
                              void* d_out, int out_size, void* d_ws, size_t ws_size,
                              hipStream_t stream) {
    const float* x           = (const float*)d_in[0];
    const float* rsign1_beta = (const float*)d_in[1];
    const float* w1          = (const float*)d_in[2];
    const float* bn1_g       = (const float*)d_in[3];
    const float* bn1_b       = (const float*)d_in[4];
    const float* bn1_m       = (const float*)d_in[5];
    const float* bn1_v       = (const float*)d_in[6];
    const float* rsign2_beta = (const float*)d_in[7];
    const float* w2          = (const float*)d_in[8];
    const float* bn2_g       = (const float*)d_in[9];
    const float* bn2_b       = (const float*)d_in[10];
    const float* bn2_m       = (const float*)d_in[11];
    const float* bn2_v       = (const float*)d_in[12];
    const float* pr_gamma    = (const float*)d_in[13];
    const float* pr_slope    = (const float*)d_in[14];
    const float* pr_zeta     = (const float*)d_in[15];

    char* ws = (char*)d_ws;
    u64*   pw1    = (u64*)(ws);            // 256*9*4*8   = 73728 B
    u64*   pw2    = (u64*)(ws + 73728);    // 256*4*8     =  8192 B
    float* scale1 = (float*)(ws + 81920);  // 1024 B each
    float* shift1 = (float*)(ws + 82944);
    float* scale2 = (float*)(ws + 83968);
    float* shift2 = (float*)(ws + 84992);
    u64*   pack1  = (u64*)(ws + 86016);    // 32*56*56*4*8 = 3211264 B

    prep_weights<<<256, 256, 0, stream>>>(w1, w2, bn1_g, bn1_b, bn1_m, bn1_v,
                                          bn2_g, bn2_b, bn2_m, bn2_v,
                                          pw1, pw2, scale1, shift1, scale2, shift2);
    pack_input<<<BB*HH, 256, 0, stream>>>(x, rsign1_beta, pack1);
    main_fused<<<BB*HH*2, 256, 0, stream>>>(x, pack1, pw1, pw2,
                                            scale1, shift1, scale2, shift2,
                                            rsign2_beta, pr_gamma, pr_slope, pr_zeta,
                                            (float*)d_out);
}